// Round 1
// baseline (462.931 us; speedup 1.0000x reference)
//
#include <hip/hip_runtime.h>
#include <hip/hip_bf16.h>

#define DI __device__ __forceinline__

typedef __attribute__((ext_vector_type(8))) __bf16 bf16x8;
typedef __attribute__((ext_vector_type(4))) float f32x4;

DI unsigned short f2bs(float f) {
  __hip_bfloat16 h = __float2bfloat16(f);
  return __builtin_bit_cast(unsigned short, h);
}
DI float bs2f(unsigned short s) {
  return __bfloat162float(__builtin_bit_cast(__hip_bfloat16, s));
}
DI f32x4 mfma16(bf16x8 a, bf16x8 b, f32x4 c) {
  return __builtin_amdgcn_mfma_f32_16x16x32_bf16(a, b, c, 0, 0, 0);
}
// async global->LDS, 16B per lane; LDS dest is wave-uniform base + lane*16
DI void g2lds16(const void* g, void* l) {
  __builtin_amdgcn_global_load_lds(
      (__attribute__((address_space(1))) void*)(unsigned long long)g,
      (__attribute__((address_space(3))) void*)l, 16, 0, 0);
}

// ---------------- weight transpose f32[K,N] -> bf16[N,K] ----------------
__global__ __launch_bounds__(256) void k_transw(const float* __restrict__ W,
                                                unsigned short* __restrict__ Wt,
                                                int K, int N) {
  __shared__ float tile[64][65];
  int tk = blockIdx.x * 64, tn = blockIdx.y * 64;
  int t = threadIdx.x;
#pragma unroll
  for (int i = 0; i < 16; ++i) {
    int idx = t + i * 256;
    int r = idx >> 6, c = idx & 63;
    tile[r][c] = W[(size_t)(tk + r) * N + tn + c];
  }
  __syncthreads();
#pragma unroll
  for (int i = 0; i < 16; ++i) {
    int idx = t + i * 256;
    int n = idx >> 6, kk = idx & 63;
    Wt[(size_t)(tn + n) * K + tk + kk] = f2bs(tile[kk][n]);
  }
}

// ---------------- LayerNorm f32[rows,512] -> bf16 ----------------
__global__ __launch_bounds__(256) void k_ln(const float* __restrict__ x,
                                            const float* __restrict__ g,
                                            const float* __restrict__ b,
                                            unsigned short* __restrict__ y) {
  int row = blockIdx.x, t = threadIdx.x;
  const float* xr = x + (size_t)row * 512;
  float a0 = xr[t], a1 = xr[t + 256];
  float s1 = a0 + a1, s2 = a0 * a0 + a1 * a1;
#pragma unroll
  for (int o = 32; o > 0; o >>= 1) {
    s1 += __shfl_down(s1, o);
    s2 += __shfl_down(s2, o);
  }
  __shared__ float r1[4], r2[4], bc[2];
  int w = t >> 6, l = t & 63;
  if (l == 0) { r1[w] = s1; r2[w] = s2; }
  __syncthreads();
  if (t == 0) {
    float t1 = r1[0] + r1[1] + r1[2] + r1[3];
    float t2 = r2[0] + r2[1] + r2[2] + r2[3];
    float m = t1 / 512.f;
    float v = t2 / 512.f - m * m;
    bc[0] = m;
    bc[1] = rsqrtf(v + 1e-5f);
  }
  __syncthreads();
  float m = bc[0], inv = bc[1];
  y[(size_t)row * 512 + t] = f2bs((a0 - m) * inv * g[t] + b[t]);
  y[(size_t)row * 512 + t + 256] = f2bs((a1 - m) * inv * g[t + 256] + b[t + 256]);
}

// ---------------- GEMM: C[M,N] = A[M,K](bf16) * Bt[N,K](bf16)^T + bias, epilogue by mode
// mode 0: outh = bf16(val)                    (K,V proj)
// mode 1: outh = bf16(val*0.125)              (Q proj, pre-scaled)
// mode 2: outf = gateY * sigmoid(val)         (GLU u)
// mode 3: outf = val + add1 + add2            (O proj + u + x -> x2)
// mode 4: outh = bf16(gelu_exact(val))        (FFN1)
// mode 5: outf = val + add1                   (FFN2 + x2 -> out)
__global__ __launch_bounds__(256) void k_gemm(
    const unsigned short* __restrict__ A, const unsigned short* __restrict__ Bt,
    const float* __restrict__ bias, int M, int N, int K, int mode,
    float* __restrict__ outf, unsigned short* __restrict__ outh,
    const float* __restrict__ add1, const float* __restrict__ add2,
    const unsigned short* __restrict__ gateY) {
  __shared__ __align__(16) unsigned short lA[128 * 64];
  __shared__ __align__(16) unsigned short lB[128 * 64];
  int t = threadIdx.x, w = t >> 6, l = t & 63;
  int m0 = blockIdx.x * 128, n0 = blockIdx.y * 128;
  int wm = (w >> 1) * 64, wn = (w & 1) * 64;
  f32x4 acc[4][4] = {};
  int srow = w * 32 + (l >> 3);
  int scolb = (l & 7) * 16;
  for (int k0 = 0; k0 < K; k0 += 64) {
#pragma unroll
    for (int c = 0; c < 4; ++c) {
      int row = srow + c * 8;
      const char* ga = (const char*)A + ((size_t)(m0 + row) * K + k0) * 2 + scolb;
      g2lds16(ga, (char*)lA + w * 4096 + c * 1024);
      const char* gb = (const char*)Bt + ((size_t)(n0 + row) * K + k0) * 2 + scolb;
      g2lds16(gb, (char*)lB + w * 4096 + c * 1024);
    }
    __syncthreads();
#pragma unroll
    for (int kc = 0; kc < 2; ++kc) {
      bf16x8 af[4], bfr[4];
#pragma unroll
      for (int i = 0; i < 4; ++i) {
        int ar = wm + i * 16 + (l & 15);
        af[i] = *(const bf16x8*)((const char*)lA + ar * 128 + kc * 64 + (l >> 4) * 16);
        int br = wn + i * 16 + (l & 15);
        bfr[i] = *(const bf16x8*)((const char*)lB + br * 128 + kc * 64 + (l >> 4) * 16);
      }
#pragma unroll
      for (int i = 0; i < 4; ++i)
#pragma unroll
        for (int j = 0; j < 4; ++j)
          acc[i][j] = mfma16(af[i], bfr[j], acc[i][j]);
    }
    __syncthreads();
  }
#pragma unroll
  for (int i = 0; i < 4; ++i) {
#pragma unroll
    for (int j = 0; j < 4; ++j) {
#pragma unroll
      for (int r = 0; r < 4; ++r) {
        int row = m0 + wm + i * 16 + (l >> 4) * 4 + r;
        int col = n0 + wn + j * 16 + (l & 15);
        size_t idx = (size_t)row * N + col;
        float val = acc[i][j][r] + bias[col];
        if (mode == 0) {
          outh[idx] = f2bs(val);
        } else if (mode == 1) {
          outh[idx] = f2bs(val * 0.125f);
        } else if (mode == 2) {
          float yv = bs2f(gateY[idx]);
          outf[idx] = yv * (1.f / (1.f + __expf(-val)));
        } else if (mode == 3) {
          outf[idx] = val + add1[idx] + add2[idx];
        } else if (mode == 4) {
          outh[idx] = f2bs(0.5f * val * (1.f + erff(val * 0.70710678f)));
        } else {
          outf[idx] = val + add1[idx];
        }
      }
    }
  }
}

// ---------------- fused flash attention ----------------
// block = (b, 16-row q tile), 8 waves, wave = head. KT=32 per iteration.
// bias tile [16][32][8] staged coalesced into LDS; V^T staged into LDS; online softmax.
__global__ __launch_bounds__(512, 4) void k_attn(
    const unsigned short* __restrict__ q, const unsigned short* __restrict__ k,
    const unsigned short* __restrict__ v, const float* __restrict__ bias,
    const unsigned char* __restrict__ mask, unsigned short* __restrict__ out) {
  __shared__ __align__(16) float ls_bias[16][32][8];
  __shared__ unsigned char ls_mask[16][32];
  __shared__ __align__(16) unsigned short ls_vt[512][32];  // [h*64+hd][k_local]
  __shared__ __align__(16) unsigned short ls_p[8][16][32]; // per-wave P tile
  int bid = blockIdx.x;
  int b = bid >> 7, q0 = (bid & 127) * 16;
  int t = threadIdx.x, w = t >> 6, l = t & 63, h = w;

  bf16x8 qa[2];
  {
    int qrow = b * 2048 + q0 + (l & 15);
#pragma unroll
    for (int kc = 0; kc < 2; ++kc)
      qa[kc] = *(const bf16x8*)(q + ((size_t)qrow * 512 + h * 64 + kc * 32 + (l >> 4) * 8));
  }
  f32x4 oacc[4] = {};
  float mrow[4], lrow[4];
#pragma unroll
  for (int r = 0; r < 4; ++r) { mrow[r] = -1e30f; lrow[r] = 0.f; }

  int sq = t >> 5, sk = t & 31;  // bias/mask staging coords
  int colg = l >> 4;

  for (int kt = 0; kt < 64; ++kt) {
    int kbase = kt * 32;
    // ---- stage bias tile (coalesced over h-contiguous layout) ----
    {
      const float* bp = bias + ((size_t)(b * 2048 + q0 + sq) * 2048 + kbase + sk) * 8;
      float4 b0 = *(const float4*)bp;
      float4 b1 = *(const float4*)(bp + 4);
      *(float4*)&ls_bias[sq][sk][0] = b0;
      *(float4*)&ls_bias[sq][sk][4] = b1;
      ls_mask[sq][sk] = mask[(size_t)(b * 2048 + q0 + sq) * 2048 + kbase + sk];
    }
    // ---- stage V^T tile ----
    {
      const unsigned short* vp = v + ((size_t)(b * 2048 + kbase) * 512 + t);
#pragma unroll
      for (int g8 = 0; g8 < 4; ++g8) {
        uint4 pk;
#pragma unroll
        for (int j = 0; j < 4; ++j) {
          unsigned lo = vp[(size_t)(g8 * 8 + 2 * j) * 512];
          unsigned hi = vp[(size_t)(g8 * 8 + 2 * j + 1) * 512];
          (&pk.x)[j] = lo | (hi << 16);
        }
        *(uint4*)&ls_vt[t][g8 * 8] = pk;
      }
    }
    __syncthreads();
    // ---- scores: S[16q x 32k] for this head ----
    f32x4 sc[2] = {};
#pragma unroll
    for (int tt = 0; tt < 2; ++tt) {
      int kpos = b * 2048 + kbase + tt * 16 + (l & 15);
#pragma unroll
      for (int kc = 0; kc < 2; ++kc) {
        bf16x8 kb = *(const bf16x8*)(k + ((size_t)kpos * 512 + h * 64 + kc * 32 + (l >> 4) * 8));
        sc[tt] = mfma16(qa[kc], kb, sc[tt]);
      }
    }
    // ---- bias + mask + online softmax ----
    float pnew[2][4], mtile[4];
#pragma unroll
    for (int r = 0; r < 4; ++r) {
      int qr = colg * 4 + r;
      float s0 = sc[0][r] + ls_bias[qr][l & 15][h];
      float s1 = sc[1][r] + ls_bias[qr][16 + (l & 15)][h];
      if (ls_mask[qr][l & 15]) s0 = -1e30f;
      if (ls_mask[qr][16 + (l & 15)]) s1 = -1e30f;
      pnew[0][r] = s0;
      pnew[1][r] = s1;
      float mx = fmaxf(s0, s1);
#pragma unroll
      for (int o = 1; o < 16; o <<= 1) mx = fmaxf(mx, __shfl_xor(mx, o));
      mtile[r] = mx;
    }
    float scale[4];
#pragma unroll
    for (int r = 0; r < 4; ++r) {
      float mn = fmaxf(mrow[r], mtile[r]);
      scale[r] = __expf(mrow[r] - mn);
      mrow[r] = mn;
      float p0 = __expf(pnew[0][r] - mn), p1 = __expf(pnew[1][r] - mn);
      pnew[0][r] = p0;
      pnew[1][r] = p1;
      float ps = p0 + p1;
#pragma unroll
      for (int o = 1; o < 16; o <<= 1) ps += __shfl_xor(ps, o);
      lrow[r] = lrow[r] * scale[r] + ps;
    }
#pragma unroll
    for (int d = 0; d < 4; ++d)
#pragma unroll
      for (int r = 0; r < 4; ++r) oacc[d][r] *= scale[r];
    // ---- P -> LDS (re-fragment for PV A-operand) ----
#pragma unroll
    for (int tt = 0; tt < 2; ++tt)
#pragma unroll
      for (int r = 0; r < 4; ++r)
        ls_p[w][colg * 4 + r][tt * 16 + (l & 15)] = f2bs(pnew[tt][r]);
    // ---- PV ----
    bf16x8 pa = *(const bf16x8*)&ls_p[w][l & 15][(l >> 4) * 8];
#pragma unroll
    for (int d = 0; d < 4; ++d) {
      bf16x8 vb = *(const bf16x8*)&ls_vt[h * 64 + d * 16 + (l & 15)][(l >> 4) * 8];
      oacc[d] = mfma16(pa, vb, oacc[d]);
    }
    __syncthreads();
  }
  // ---- epilogue: normalize and store bf16 [4096, 512] ----
#pragma unroll
  for (int d = 0; d < 4; ++d)
#pragma unroll
    for (int r = 0; r < 4; ++r) {
      int row = b * 2048 + q0 + (l >> 4) * 4 + r;
      int col = h * 64 + d * 16 + (l & 15);
      out[(size_t)row * 512 + col] = f2bs(oacc[d][r] / lrow[r]);
    }
}

extern "C" void kernel_launch(void* const* d_in, const int* in_sizes, int n_in,
                              void* d_out, int out_size, void* d_ws, size_t ws_size,
                              hipStream_t stream) {
  (void)in_sizes; (void)n_in; (void)out_size; (void)ws_size;
  const float* x = (const float*)d_in[0];
  const float* abias = (const float*)d_in[1];
  const unsigned char* amask = (const unsigned char*)d_in[2];
  const float* Wq = (const float*)d_in[3];
  const float* bq = (const float*)d_in[4];
  const float* Wk = (const float*)d_in[5];
  const float* bk = (const float*)d_in[6];
  const float* Wv = (const float*)d_in[7];
  const float* bv = (const float*)d_in[8];
  const float* Wg = (const float*)d_in[9];
  const float* bg = (const float*)d_in[10];
  const float* Wo = (const float*)d_in[11];
  const float* bo = (const float*)d_in[12];
  const float* ln1g = (const float*)d_in[13];
  const float* ln1b = (const float*)d_in[14];
  const float* ln2g = (const float*)d_in[15];
  const float* ln2b = (const float*)d_in[16];
  const float* W1 = (const float*)d_in[17];
  const float* b1 = (const float*)d_in[18];
  const float* W2 = (const float*)d_in[19];
  const float* b2 = (const float*)d_in[20];
  float* outp = (float*)d_out;

  char* ws = (char*)d_ws;
  const size_t MB = 1024 * 1024;
  // region A (16MB): q,k,v,attn_o projections; later reused as h1
  unsigned short* qb = (unsigned short*)(ws + 0);
  unsigned short* kb = (unsigned short*)(ws + 4 * MB);
  unsigned short* vb = (unsigned short*)(ws + 8 * MB);
  unsigned short* ao = (unsigned short*)(ws + 12 * MB);
  unsigned short* h1 = (unsigned short*)(ws + 0);  // aliases q/k/v/ao (dead by then)
  unsigned short* y1 = (unsigned short*)(ws + 16 * MB);  // also reused as y2
  float* u = (float*)(ws + 20 * MB);
  float* x2 = (float*)(ws + 28 * MB);
  unsigned short* wqt = (unsigned short*)(ws + 36 * MB);
  unsigned short* wkt = (unsigned short*)(ws + 36 * MB + 512 * 1024);
  unsigned short* wvt = (unsigned short*)(ws + 37 * MB);
  unsigned short* wgt = (unsigned short*)(ws + 37 * MB + 512 * 1024);
  unsigned short* wot = (unsigned short*)(ws + 38 * MB);
  unsigned short* w1t = (unsigned short*)(ws + 38 * MB + 512 * 1024);  // [2048,512] 2MB
  unsigned short* w2t = (unsigned short*)(ws + 40 * MB + 512 * 1024);  // [512,2048] 2MB

  // weight transposes (f32 [K,N] -> bf16 [N,K])
  k_transw<<<dim3(8, 8), 256, 0, stream>>>(Wq, wqt, 512, 512);
  k_transw<<<dim3(8, 8), 256, 0, stream>>>(Wk, wkt, 512, 512);
  k_transw<<<dim3(8, 8), 256, 0, stream>>>(Wv, wvt, 512, 512);
  k_transw<<<dim3(8, 8), 256, 0, stream>>>(Wg, wgt, 512, 512);
  k_transw<<<dim3(8, 8), 256, 0, stream>>>(Wo, wot, 512, 512);
  k_transw<<<dim3(8, 32), 256, 0, stream>>>(W1, w1t, 512, 2048);
  k_transw<<<dim3(32, 8), 256, 0, stream>>>(W2, w2t, 2048, 512);

  // LN1
  k_ln<<<4096, 256, 0, stream>>>(x, ln1g, ln1b, y1);
  // projections
  k_gemm<<<dim3(32, 4), 256, 0, stream>>>(y1, wqt, bq, 4096, 512, 512, 1, nullptr, qb,
                                          nullptr, nullptr, nullptr);
  k_gemm<<<dim3(32, 4), 256, 0, stream>>>(y1, wkt, bk, 4096, 512, 512, 0, nullptr, kb,
                                          nullptr, nullptr, nullptr);
  k_gemm<<<dim3(32, 4), 256, 0, stream>>>(y1, wvt, bv, 4096, 512, 512, 0, nullptr, vb,
                                          nullptr, nullptr, nullptr);
  k_gemm<<<dim3(32, 4), 256, 0, stream>>>(y1, wgt, bg, 4096, 512, 512, 2, u, nullptr,
                                          nullptr, nullptr, y1);
  // attention
  k_attn<<<256, 512, 0, stream>>>(qb, kb, vb, abias, amask, ao);
  // O projection + u + x -> x2
  k_gemm<<<dim3(32, 4), 256, 0, stream>>>(ao, wot, bo, 4096, 512, 512, 3, x2, nullptr,
                                          u, x, nullptr);
  // LN2 (y2 aliases y1)
  k_ln<<<4096, 256, 0, stream>>>(x2, ln2g, ln2b, y1);
  // FFN
  k_gemm<<<dim3(32, 16), 256, 0, stream>>>(y1, w1t, b1, 4096, 2048, 512, 4, nullptr, h1,
                                           nullptr, nullptr, nullptr);
  k_gemm<<<dim3(32, 4), 256, 0, stream>>>(h1, w2t, b2, 4096, 512, 2048, 5, outp, nullptr,
                                          x2, nullptr, nullptr);
}

// Round 2
// 399.360 us; speedup vs baseline: 1.1592x; 1.1592x over previous
//
#include <hip/hip_runtime.h>
#include <hip/hip_bf16.h>

#define DI __device__ __forceinline__

typedef __attribute__((ext_vector_type(8))) __bf16 bf16x8;
typedef __attribute__((ext_vector_type(4))) float f32x4;
typedef __attribute__((ext_vector_type(4))) unsigned short u16x4;

DI unsigned short f2bs(float f) {
  __hip_bfloat16 h = __float2bfloat16(f);
  return __builtin_bit_cast(unsigned short, h);
}
DI float bs2f(unsigned short s) {
  return __bfloat162float(__builtin_bit_cast(__hip_bfloat16, s));
}
DI f32x4 mfma16(bf16x8 a, bf16x8 b, f32x4 c) {
  return __builtin_amdgcn_mfma_f32_16x16x32_bf16(a, b, c, 0, 0, 0);
}
DI void g2lds16(const void* g, void* l) {
  __builtin_amdgcn_global_load_lds(
      (__attribute__((address_space(1))) void*)(unsigned long long)g,
      (__attribute__((address_space(3))) void*)l, 16, 0, 0);
}

// ---------------- weight transpose f32[K,N] -> bf16[N,K] ----------------
__global__ __launch_bounds__(256) void k_transw(const float* __restrict__ W,
                                                unsigned short* __restrict__ Wt,
                                                int K, int N) {
  __shared__ float tile[64][65];
  int tk = blockIdx.x * 64, tn = blockIdx.y * 64;
  int t = threadIdx.x;
#pragma unroll
  for (int i = 0; i < 16; ++i) {
    int idx = t + i * 256;
    int r = idx >> 6, c = idx & 63;
    tile[r][c] = W[(size_t)(tk + r) * N + tn + c];
  }
  __syncthreads();
#pragma unroll
  for (int i = 0; i < 16; ++i) {
    int idx = t + i * 256;
    int n = idx >> 6, kk = idx & 63;
    Wt[(size_t)(tn + n) * K + tk + kk] = f2bs(tile[kk][n]);
  }
}

// ---------------- bias concat [bq|bk|bv|bg] -> bcat[2048] ----------------
__global__ __launch_bounds__(256) void k_bcat(const float* __restrict__ bq,
                                              const float* __restrict__ bk,
                                              const float* __restrict__ bv,
                                              const float* __restrict__ bg,
                                              float* __restrict__ bcat) {
  int t = blockIdx.x * 256 + threadIdx.x;
  const float* src = t < 512 ? bq : t < 1024 ? bk : t < 1536 ? bv : bg;
  bcat[t] = src[t & 511];
}

// ---------------- LayerNorm f32[rows,512] -> bf16 ----------------
__global__ __launch_bounds__(256) void k_ln(const float* __restrict__ x,
                                            const float* __restrict__ g,
                                            const float* __restrict__ b,
                                            unsigned short* __restrict__ y) {
  int row = blockIdx.x, t = threadIdx.x;
  const float* xr = x + (size_t)row * 512;
  float a0 = xr[t], a1 = xr[t + 256];
  float s1 = a0 + a1, s2 = a0 * a0 + a1 * a1;
#pragma unroll
  for (int o = 32; o > 0; o >>= 1) {
    s1 += __shfl_down(s1, o);
    s2 += __shfl_down(s2, o);
  }
  __shared__ float r1[4], r2[4], bc[2];
  int w = t >> 6, l = t & 63;
  if (l == 0) { r1[w] = s1; r2[w] = s2; }
  __syncthreads();
  if (t == 0) {
    float t1 = r1[0] + r1[1] + r1[2] + r1[3];
    float t2 = r2[0] + r2[1] + r2[2] + r2[3];
    float m = t1 / 512.f;
    float v = t2 / 512.f - m * m;
    bc[0] = m;
    bc[1] = rsqrtf(v + 1e-5f);
  }
  __syncthreads();
  float m = bc[0], inv = bc[1];
  y[(size_t)row * 512 + t] = f2bs((a0 - m) * inv * g[t] + b[t]);
  y[(size_t)row * 512 + t + 256] = f2bs((a1 - m) * inv * g[t + 256] + b[t + 256]);
}

// ---------------- GEMM: C[M,N] = A[M,K](bf16) * Bt[N,K]^T + bias ----------------
// mode 3: outf = val + add1 + add2            (O proj + u + x -> x2)
// mode 4: outh = bf16(gelu_exact(val))        (FFN1)
// mode 5: outf = val + add1                   (FFN2 + x2 -> out)
// mode 6: fused QKVG: col<512 -> q(scaled) ; <1024 -> k ; <1536 -> V^T ; else u=y*sigmoid
template <int BM>
__global__ __launch_bounds__(256) void k_gemm(
    const unsigned short* __restrict__ A, const unsigned short* __restrict__ Bt,
    const float* __restrict__ bias, int M, int N, int K, int mode,
    float* __restrict__ outf, unsigned short* __restrict__ outh,
    const float* __restrict__ add1, const float* __restrict__ add2,
    unsigned short* __restrict__ vtout) {
  constexpr int MI = BM / 32;          // A-frags per wave
  __shared__ __align__(16) unsigned short lA[BM * 64];
  __shared__ __align__(16) unsigned short lB[64 * 64];
  int t = threadIdx.x, w = t >> 6, l = t & 63;
  int l15 = l & 15, lg = l >> 4;
  int m0 = blockIdx.x * BM, n0 = blockIdx.y * 64;
  int wm = (w >> 1) * (BM / 2), wn = (w & 1) * 32;
  f32x4 acc[MI][2] = {};
  int sr = l >> 3, scb = (l & 7) * 16;
  for (int k0 = 0; k0 < K; k0 += 64) {
#pragma unroll
    for (int c = 0; c < MI; ++c) {
      int row = w * (BM / 4) + sr + c * 8;
      g2lds16((const char*)A + ((size_t)(m0 + row) * K + k0) * 2 + scb,
              (char*)lA + w * (BM / 4) * 128 + c * 1024);
    }
#pragma unroll
    for (int c = 0; c < 2; ++c) {
      int row = w * 16 + sr + c * 8;
      g2lds16((const char*)Bt + ((size_t)(n0 + row) * K + k0) * 2 + scb,
              (char*)lB + w * 2048 + c * 1024);
    }
    __syncthreads();
#pragma unroll
    for (int kc = 0; kc < 2; ++kc) {
      bf16x8 af[MI], bfr[2];
#pragma unroll
      for (int i = 0; i < MI; ++i)
        af[i] = *(const bf16x8*)((const char*)lA + (wm + i * 16 + l15) * 128 + kc * 64 + lg * 16);
#pragma unroll
      for (int j = 0; j < 2; ++j)
        bfr[j] = *(const bf16x8*)((const char*)lB + (wn + j * 16 + l15) * 128 + kc * 64 + lg * 16);
#pragma unroll
      for (int i = 0; i < MI; ++i)
#pragma unroll
        for (int j = 0; j < 2; ++j)
          acc[i][j] = mfma16(af[i], bfr[j], acc[i][j]);
    }
    __syncthreads();
  }
#pragma unroll
  for (int i = 0; i < MI; ++i) {
#pragma unroll
    for (int j = 0; j < 2; ++j) {
      int col = n0 + wn + j * 16 + l15;
      int row0 = m0 + wm + i * 16 + lg * 4;
      float vals[4];
#pragma unroll
      for (int r = 0; r < 4; ++r) vals[r] = acc[i][j][r] + bias[col];
      if (mode == 6) {
        int sel = col >> 9, c5 = col & 511;
        if (sel == 2) {  // V -> VT[b][h][d][n], pack 4 consecutive n
          int hh = c5 >> 6, dd = c5 & 63, bb = row0 >> 11, nn = row0 & 2047;
          u16x4 pk;
#pragma unroll
          for (int r = 0; r < 4; ++r) pk[r] = f2bs(vals[r]);
          *(u16x4*)(vtout + (((size_t)(bb * 8 + hh) * 64 + dd) * 2048 + nn)) = pk;
        } else {
#pragma unroll
          for (int r = 0; r < 4; ++r) {
            size_t idx = (size_t)(row0 + r) * 512 + c5;
            if (sel == 0) outh[idx] = f2bs(vals[r] * 0.125f);
            else if (sel == 1) outh[2097152 + idx] = f2bs(vals[r]);
            else outf[idx] = bs2f(A[idx]) * (1.f / (1.f + __expf(-vals[r])));
          }
        }
      } else {
#pragma unroll
        for (int r = 0; r < 4; ++r) {
          size_t idx = (size_t)(row0 + r) * N + col;
          if (mode == 3) outf[idx] = vals[r] + add1[idx] + add2[idx];
          else if (mode == 4) outh[idx] = f2bs(0.5f * vals[r] * (1.f + erff(vals[r] * 0.70710678f)));
          else outf[idx] = vals[r] + add1[idx];
        }
      }
    }
  }
}

// ---------------- flash attention, no-barrier k-loop, k-split ----------------
// block = 256 thr (4 waves = 4 heads), work = (b, q-tile16, ksplit, hhalf)
template <int NKS>
__global__ __launch_bounds__(256, 4) void k_attn2(
    const unsigned short* __restrict__ q, const unsigned short* __restrict__ kk,
    const unsigned short* __restrict__ vt, const float* __restrict__ bias,
    const unsigned char* __restrict__ mask, unsigned short* __restrict__ opart,
    float* __restrict__ mpart, float* __restrict__ lpart,
    unsigned short* __restrict__ ao) {
  __shared__ unsigned short ls_p[4][16][36];
  const int nblk = 512 * NKS;
  int bid = blockIdx.x;
  int wkid = (bid & 7) * (nblk / 8) + (bid >> 3);  // bijective XCD swizzle
  int hh = wkid & 1;
  int ksp = (wkid >> 1) % NKS;
  int rest = (wkid >> 1) / NKS;  // b*128 + qt
  int qt = rest & 127, b = rest >> 7;
  int q0 = qt * 16;
  int t = threadIdx.x, w = t >> 6, l = t & 63;
  int l15 = l & 15, lg = l >> 4;
  int h = hh * 4 + w;

  bf16x8 qa[2];
#pragma unroll
  for (int kc = 0; kc < 2; ++kc)
    qa[kc] = *(const bf16x8*)(q + ((size_t)(b * 2048 + q0 + l15) * 512 + h * 64 + kc * 32 + lg * 8));

  f32x4 oacc[4] = {};
  float mrow[4], lrow[4];
#pragma unroll
  for (int r = 0; r < 4; ++r) { mrow[r] = -3e38f; lrow[r] = 0.f; }

  const int kbase0 = ksp * (2048 / NKS);
  const int iters = 2048 / NKS / 32;
  const unsigned short* vbase = vt + ((size_t)(b * 8 + h) * 64) * 2048;

  for (int it = 0; it < iters; ++it) {
    int kb0 = kbase0 + it * 32;
    // ---- QK^T: S[16q x 32k] ----
    f32x4 sc[2] = {};
#pragma unroll
    for (int tt = 0; tt < 2; ++tt) {
      const unsigned short* kp =
          kk + ((size_t)(b * 2048 + kb0 + tt * 16 + l15) * 512 + h * 64 + lg * 8);
      sc[tt] = mfma16(qa[0], *(const bf16x8*)kp, sc[tt]);
      sc[tt] = mfma16(qa[1], *(const bf16x8*)(kp + 32), sc[tt]);
    }
    // ---- bias + mask (direct global; block-level L1/L2 reuse) ----
    float s0v[4], s1v[4], mtile[4];
#pragma unroll
    for (int r = 0; r < 4; ++r) {
      size_t grow = (size_t)(b * 2048 + q0 + lg * 4 + r) * 2048 + kb0;
      float b0 = bias[(grow + l15) * 8 + h];
      float b1 = bias[(grow + 16 + l15) * 8 + h];
      float s0 = sc[0][r] + b0, s1 = sc[1][r] + b1;
      if (mask[grow + l15]) s0 = -3e38f;
      if (mask[grow + 16 + l15]) s1 = -3e38f;
      s0v[r] = s0; s1v[r] = s1;
      float mx = fmaxf(s0, s1);
#pragma unroll
      for (int o = 1; o < 16; o <<= 1) mx = fmaxf(mx, __shfl_xor(mx, o));
      mtile[r] = mx;
    }
    float scale[4];
#pragma unroll
    for (int r = 0; r < 4; ++r) {
      float mn = fmaxf(mrow[r], mtile[r]);
      scale[r] = __expf(mrow[r] - mn);
      mrow[r] = mn;
      float p0 = __expf(s0v[r] - mn), p1 = __expf(s1v[r] - mn);
      s0v[r] = p0; s1v[r] = p1;
      float ps = p0 + p1;
#pragma unroll
      for (int o = 1; o < 16; o <<= 1) ps += __shfl_xor(ps, o);
      lrow[r] = lrow[r] * scale[r] + ps;
    }
#pragma unroll
    for (int d = 0; d < 4; ++d)
#pragma unroll
      for (int r = 0; r < 4; ++r) oacc[d][r] *= scale[r];
    // ---- P -> per-wave LDS (re-fragment), no block barrier needed ----
#pragma unroll
    for (int r = 0; r < 4; ++r) {
      ls_p[w][lg * 4 + r][l15] = f2bs(s0v[r]);
      ls_p[w][lg * 4 + r][16 + l15] = f2bs(s1v[r]);
    }
    bf16x8 pa = *(const bf16x8*)&ls_p[w][l15][lg * 8];
    // ---- PV: B-frags straight from global VT ----
#pragma unroll
    for (int d = 0; d < 4; ++d) {
      const unsigned short* vp = vbase + ((size_t)(d * 16 + l15) * 2048 + kb0 + lg * 8);
      oacc[d] = mfma16(pa, *(const bf16x8*)vp, oacc[d]);
    }
  }
  // ---- epilogue ----
  if (NKS == 1) {
#pragma unroll
    for (int d = 0; d < 4; ++d)
#pragma unroll
      for (int r = 0; r < 4; ++r) {
        size_t row = (size_t)(b * 2048 + q0 + lg * 4 + r);
        ao[row * 512 + h * 64 + d * 16 + l15] = f2bs(oacc[d][r] / lrow[r]);
      }
  } else {
#pragma unroll
    for (int d = 0; d < 4; ++d)
#pragma unroll
      for (int r = 0; r < 4; ++r) {
        size_t row = (size_t)(ksp * 4096 + b * 2048 + q0 + lg * 4 + r);
        opart[row * 512 + h * 64 + d * 16 + l15] = f2bs(oacc[d][r]);
      }
    if (l15 == 0) {
#pragma unroll
      for (int r = 0; r < 4; ++r) {
        size_t row = (size_t)(ksp * 4096 + b * 2048 + q0 + lg * 4 + r);
        mpart[row * 8 + h] = mrow[r];
        lpart[row * 8 + h] = lrow[r];
      }
    }
  }
}

// ---------------- combine k-split partials ----------------
__global__ __launch_bounds__(256) void k_comb(const unsigned short* __restrict__ op,
                                              const float* __restrict__ mp,
                                              const float* __restrict__ lp,
                                              unsigned short* __restrict__ ao) {
  int row = blockIdx.x, t = threadIdx.x;
  for (int c = t; c < 512; c += 256) {
    int h = c >> 6;
    float m1 = mp[(size_t)row * 8 + h], m2 = mp[(size_t)(4096 + row) * 8 + h];
    float l1 = lp[(size_t)row * 8 + h], l2 = lp[(size_t)(4096 + row) * 8 + h];
    float M = fmaxf(m1, m2);
    float e1 = __expf(m1 - M), e2 = __expf(m2 - M);
    float L = l1 * e1 + l2 * e2;
    float o = (bs2f(op[(size_t)row * 512 + c]) * e1 +
               bs2f(op[(size_t)(4096 + row) * 512 + c]) * e2) / L;
    ao[(size_t)row * 512 + c] = f2bs(o);
  }
}

extern "C" void kernel_launch(void* const* d_in, const int* in_sizes, int n_in,
                              void* d_out, int out_size, void* d_ws, size_t ws_size,
                              hipStream_t stream) {
  (void)in_sizes; (void)n_in; (void)out_size; (void)ws_size;
  const float* x = (const float*)d_in[0];
  const float* abias = (const float*)d_in[1];
  const unsigned char* amask = (const unsigned char*)d_in[2];
  const float* Wq = (const float*)d_in[3];
  const float* bq = (const float*)d_in[4];
  const float* Wk = (const float*)d_in[5];
  const float* bk = (const float*)d_in[6];
  const float* Wv = (const float*)d_in[7];
  const float* bv = (const float*)d_in[8];
  const float* Wg = (const float*)d_in[9];
  const float* bg = (const float*)d_in[10];
  const float* Wo = (const float*)d_in[11];
  const float* bo = (const float*)d_in[12];
  const float* ln1g = (const float*)d_in[13];
  const float* ln1b = (const float*)d_in[14];
  const float* ln2g = (const float*)d_in[15];
  const float* ln2b = (const float*)d_in[16];
  const float* W1 = (const float*)d_in[17];
  const float* b1 = (const float*)d_in[18];
  const float* W2 = (const float*)d_in[19];
  const float* b2 = (const float*)d_in[20];
  float* outp = (float*)d_out;

  char* ws = (char*)d_ws;
  const size_t MB = 1024 * 1024;
  unsigned short* qb = (unsigned short*)(ws + 0);            // 4MB [4096][512]
  // kb = qb + 2M elems (at 4MB)
  unsigned short* ao = (unsigned short*)(ws + 8 * MB);       // 4MB
  unsigned short* opart = (unsigned short*)(ws + 12 * MB);   // 8MB [2][4096][512] (12-16 free + y1 dead)
  unsigned short* y1 = (unsigned short*)(ws + 16 * MB);      // 4MB
  unsigned short* h1 = (unsigned short*)(ws + 0);            // 16MB (FFN phase, spans 0-16)
  float* u = (float*)(ws + 20 * MB);                         // 8MB f32
  unsigned short* wcat = (unsigned short*)(ws + 28 * MB);    // 2MB [2048][512]
  unsigned short* wot = (unsigned short*)(ws + 30 * MB);     // 0.5MB
  unsigned short* w1t = (unsigned short*)(ws + 30 * MB + 512 * 1024);  // 2MB
  unsigned short* w2t = (unsigned short*)(ws + 32 * MB + 512 * 1024);  // 2MB
  float* bcat = (float*)(ws + 35 * MB);                      // 8KB
  float* mpart = (float*)(ws + 35 * MB + 256 * 1024);        // 256KB
  float* lpart = (float*)(ws + 35 * MB + 512 * 1024);        // 256KB
  unsigned short* vtb = (unsigned short*)(ws + 36 * MB);     // 4MB [2][8][64][2048]
  float* x2 = (float*)d_out;                                 // x2 lives in d_out

  // weight transposes into concat layout
  k_transw<<<dim3(8, 8), 256, 0, stream>>>(Wq, wcat + 0 * 512 * 512, 512, 512);
  k_transw<<<dim3(8, 8), 256, 0, stream>>>(Wk, wcat + 1 * 512 * 512, 512, 512);
  k_transw<<<dim3(8, 8), 256, 0, stream>>>(Wv, wcat + 2 * 512 * 512, 512, 512);
  k_transw<<<dim3(8, 8), 256, 0, stream>>>(Wg, wcat + 3 * 512 * 512, 512, 512);
  k_transw<<<dim3(8, 8), 256, 0, stream>>>(Wo, wot, 512, 512);
  k_transw<<<dim3(8, 32), 256, 0, stream>>>(W1, w1t, 512, 2048);
  k_transw<<<dim3(32, 8), 256, 0, stream>>>(W2, w2t, 2048, 512);
  k_bcat<<<8, 256, 0, stream>>>(bq, bk, bv, bg, bcat);

  // LN1
  k_ln<<<4096, 256, 0, stream>>>(x, ln1g, ln1b, y1);
  // fused QKVG projection (q scaled, k, V^T, u = y*sigmoid(g))
  k_gemm<128><<<dim3(32, 32), 256, 0, stream>>>(y1, wcat, bcat, 4096, 2048, 512, 6,
                                                u, qb, nullptr, nullptr, vtb);
  // attention (k-split 2) + combine
  k_attn2<2><<<1024, 256, 0, stream>>>(qb, qb + 2097152, vtb, abias, amask,
                                       opart, mpart, lpart, ao);
  k_comb<<<4096, 256, 0, stream>>>(opart, mpart, lpart, ao);
  // O projection + u + x -> x2 (in d_out)
  k_gemm<64><<<dim3(64, 8), 256, 0, stream>>>(ao, wot, bo, 4096, 512, 512, 3,
                                              x2, nullptr, u, x, nullptr);
  // LN2
  k_ln<<<4096, 256, 0, stream>>>(x2, ln2g, ln2b, y1);
  // FFN
  k_gemm<128><<<dim3(32, 32), 256, 0, stream>>>(y1, w1t, b1, 4096, 2048, 512, 4,
                                                nullptr, h1, nullptr, nullptr, nullptr);
  k_gemm<64><<<dim3(64, 8), 256, 0, stream>>>(h1, w2t, b2, 4096, 512, 2048, 5,
                                              outp, nullptr, x2, nullptr, nullptr);
}

// Round 3
// 371.780 us; speedup vs baseline: 1.2452x; 1.0742x over previous
//
#include <hip/hip_runtime.h>
#include <hip/hip_bf16.h>

#define DI __device__ __forceinline__

typedef __attribute__((ext_vector_type(8))) __bf16 bf16x8;
typedef __attribute__((ext_vector_type(4))) float f32x4;
typedef __attribute__((ext_vector_type(4))) unsigned short u16x4;

DI unsigned short f2bs(float f) {
  __hip_bfloat16 h = __float2bfloat16(f);
  return __builtin_bit_cast(unsigned short, h);
}
DI float bs2f(unsigned short s) {
  return __bfloat162float(__builtin_bit_cast(__hip_bfloat16, s));
}
DI f32x4 mfma16(bf16x8 a, bf16x8 b, f32x4 c) {
  return __builtin_amdgcn_mfma_f32_16x16x32_bf16(a, b, c, 0, 0, 0);
}
DI void g2lds16(const void* g, void* l) {
  __builtin_amdgcn_global_load_lds(
      (__attribute__((address_space(1))) void*)(unsigned long long)g,
      (__attribute__((address_space(3))) void*)l, 16, 0, 0);
}

// ---------------- weight transpose f32[K,N] -> bf16[N,K] ----------------
__global__ __launch_bounds__(256) void k_transw(const float* __restrict__ W,
                                                unsigned short* __restrict__ Wt,
                                                int K, int N) {
  __shared__ float tile[64][65];
  int tk = blockIdx.x * 64, tn = blockIdx.y * 64;
  int t = threadIdx.x;
#pragma unroll
  for (int i = 0; i < 16; ++i) {
    int idx = t + i * 256;
    int r = idx >> 6, c = idx & 63;
    tile[r][c] = W[(size_t)(tk + r) * N + tn + c];
  }
  __syncthreads();
#pragma unroll
  for (int i = 0; i < 16; ++i) {
    int idx = t + i * 256;
    int n = idx >> 6, kk = idx & 63;
    Wt[(size_t)(tn + n) * K + tk + kk] = f2bs(tile[kk][n]);
  }
}

// ---------------- bias concat [bq|bk|bv|bg] -> bcat[2048] ----------------
__global__ __launch_bounds__(256) void k_bcat(const float* __restrict__ bq,
                                              const float* __restrict__ bk,
                                              const float* __restrict__ bv,
                                              const float* __restrict__ bg,
                                              float* __restrict__ bcat) {
  int t = blockIdx.x * 256 + threadIdx.x;
  const float* src = t < 512 ? bq : t < 1024 ? bk : t < 1536 ? bv : bg;
  bcat[t] = src[t & 511];
}

// ---------------- attn-bias transpose+mask-fold+interleave ----------------
// in:  bias [B,Nq,Nk,H] f32, mask [B,Nq,Nk] u8
// out: biasT [B,H,Nq,Nk'] bf16, where within each 32-col chunk the order is
//      (c0,c16,c1,c17,...,c15,c31) so a dword at pair-index p holds cols (p, p+16).
__global__ __launch_bounds__(256) void k_btrans(const float* __restrict__ bias,
                                                const unsigned char* __restrict__ mask,
                                                unsigned short* __restrict__ biasT) {
  int bid = blockIdx.x;
  int kc0 = (bid & 7) * 256;
  int row = (bid >> 3) & 2047;
  int b = bid >> 14;
  int t = threadIdx.x, h = t & 7, g = t >> 3;
  int base2 = kc0 + (g >> 2) * 32 + (g & 3) * 4;
  size_t rowoff = (size_t)(b * 2048 + row) * 2048;
  size_t gidx = (rowoff + base2) * 8 + h;
  unsigned m_lo = *(const unsigned*)(mask + rowoff + base2);
  unsigned m_hi = *(const unsigned*)(mask + rowoff + base2 + 16);
  u16x4 pk[2];
#pragma unroll
  for (int j = 0; j < 4; ++j) {
    float lo = bias[gidx + (size_t)j * 8];
    float hi = bias[gidx + 128 + (size_t)j * 8];
    if ((m_lo >> (8 * j)) & 255) lo = -1e30f;
    if ((m_hi >> (8 * j)) & 255) hi = -1e30f;
    pk[j >> 1][(j & 1) * 2] = f2bs(lo);
    pk[j >> 1][(j & 1) * 2 + 1] = f2bs(hi);
  }
  unsigned short* dst = biasT + ((size_t)(b * 8 + h) * 2048 + row) * 2048 + kc0 + g * 8;
  *(u16x4*)dst = pk[0];
  *(u16x4*)(dst + 4) = pk[1];
}

// ---------------- LayerNorm f32[rows,512] -> bf16 ----------------
__global__ __launch_bounds__(256) void k_ln(const float* __restrict__ x,
                                            const float* __restrict__ g,
                                            const float* __restrict__ b,
                                            unsigned short* __restrict__ y) {
  int row = blockIdx.x, t = threadIdx.x;
  const float* xr = x + (size_t)row * 512;
  float a0 = xr[t], a1 = xr[t + 256];
  float s1 = a0 + a1, s2 = a0 * a0 + a1 * a1;
#pragma unroll
  for (int o = 32; o > 0; o >>= 1) {
    s1 += __shfl_down(s1, o);
    s2 += __shfl_down(s2, o);
  }
  __shared__ float r1[4], r2[4], bc[2];
  int w = t >> 6, l = t & 63;
  if (l == 0) { r1[w] = s1; r2[w] = s2; }
  __syncthreads();
  if (t == 0) {
    float t1 = r1[0] + r1[1] + r1[2] + r1[3];
    float t2 = r2[0] + r2[1] + r2[2] + r2[3];
    float m = t1 / 512.f;
    float v = t2 / 512.f - m * m;
    bc[0] = m;
    bc[1] = rsqrtf(v + 1e-5f);
  }
  __syncthreads();
  float m = bc[0], inv = bc[1];
  y[(size_t)row * 512 + t] = f2bs((a0 - m) * inv * g[t] + b[t]);
  y[(size_t)row * 512 + t + 256] = f2bs((a1 - m) * inv * g[t + 256] + b[t + 256]);
}

// ---------------- GEMM: C[M,N] = A[M,K](bf16) * Bt[N,K]^T + bias ----------------
template <int BM>
__global__ __launch_bounds__(256) void k_gemm(
    const unsigned short* __restrict__ A, const unsigned short* __restrict__ Bt,
    const float* __restrict__ bias, int M, int N, int K, int mode,
    float* __restrict__ outf, unsigned short* __restrict__ outh,
    const float* __restrict__ add1, const float* __restrict__ add2,
    unsigned short* __restrict__ vtout) {
  constexpr int MI = BM / 32;
  __shared__ __align__(16) unsigned short lA[BM * 64];
  __shared__ __align__(16) unsigned short lB[64 * 64];
  int t = threadIdx.x, w = t >> 6, l = t & 63;
  int l15 = l & 15, lg = l >> 4;
  int m0 = blockIdx.x * BM, n0 = blockIdx.y * 64;
  int wm = (w >> 1) * (BM / 2), wn = (w & 1) * 32;
  f32x4 acc[MI][2] = {};
  int sr = l >> 3, scb = (l & 7) * 16;
  for (int k0 = 0; k0 < K; k0 += 64) {
#pragma unroll
    for (int c = 0; c < MI; ++c) {
      int row = w * (BM / 4) + sr + c * 8;
      g2lds16((const char*)A + ((size_t)(m0 + row) * K + k0) * 2 + scb,
              (char*)lA + w * (BM / 4) * 128 + c * 1024);
    }
#pragma unroll
    for (int c = 0; c < 2; ++c) {
      int row = w * 16 + sr + c * 8;
      g2lds16((const char*)Bt + ((size_t)(n0 + row) * K + k0) * 2 + scb,
              (char*)lB + w * 2048 + c * 1024);
    }
    __syncthreads();
#pragma unroll
    for (int kc = 0; kc < 2; ++kc) {
      bf16x8 af[MI], bfr[2];
#pragma unroll
      for (int i = 0; i < MI; ++i)
        af[i] = *(const bf16x8*)((const char*)lA + (wm + i * 16 + l15) * 128 + kc * 64 + lg * 16);
#pragma unroll
      for (int j = 0; j < 2; ++j)
        bfr[j] = *(const bf16x8*)((const char*)lB + (wn + j * 16 + l15) * 128 + kc * 64 + lg * 16);
#pragma unroll
      for (int i = 0; i < MI; ++i)
#pragma unroll
        for (int j = 0; j < 2; ++j)
          acc[i][j] = mfma16(af[i], bfr[j], acc[i][j]);
    }
    __syncthreads();
  }
#pragma unroll
  for (int i = 0; i < MI; ++i) {
#pragma unroll
    for (int j = 0; j < 2; ++j) {
      int col = n0 + wn + j * 16 + l15;
      int row0 = m0 + wm + i * 16 + lg * 4;
      float vals[4];
#pragma unroll
      for (int r = 0; r < 4; ++r) vals[r] = acc[i][j][r] + bias[col];
      if (mode == 6) {
        int sel = col >> 9, c5 = col & 511;
        if (sel == 2) {
          int hh = c5 >> 6, dd = c5 & 63, bb = row0 >> 11, nn = row0 & 2047;
          u16x4 pk;
#pragma unroll
          for (int r = 0; r < 4; ++r) pk[r] = f2bs(vals[r]);
          *(u16x4*)(vtout + (((size_t)(bb * 8 + hh) * 64 + dd) * 2048 + nn)) = pk;
        } else {
#pragma unroll
          for (int r = 0; r < 4; ++r) {
            size_t idx = (size_t)(row0 + r) * 512 + c5;
            if (sel == 0) outh[idx] = f2bs(vals[r] * 0.125f);
            else if (sel == 1) outh[2097152 + idx] = f2bs(vals[r]);
            else outf[idx] = bs2f(A[idx]) * (1.f / (1.f + __expf(-vals[r])));
          }
        }
      } else {
#pragma unroll
        for (int r = 0; r < 4; ++r) {
          size_t idx = (size_t)(row0 + r) * N + col;
          if (mode == 3) outf[idx] = vals[r] + add1[idx] + add2[idx];
          else if (mode == 4) outh[idx] = f2bs(0.5f * vals[r] * (1.f + erff(vals[r] * 0.70710678f)));
          else outf[idx] = vals[r] + add1[idx];
        }
      }
    }
  }
}

// ---------------- flash attention v3: bf16 biasT planes, no mask, k-split ----------------
template <int NKS>
__global__ __launch_bounds__(256, 8) void k_attn3(
    const unsigned short* __restrict__ q, const unsigned short* __restrict__ kk,
    const unsigned short* __restrict__ vt, const unsigned short* __restrict__ biasT,
    unsigned short* __restrict__ opart, float* __restrict__ mpart,
    float* __restrict__ lpart) {
  __shared__ unsigned short ls_p[4][16][36];
  const int nblk = 512 * NKS;
  int bid = blockIdx.x;
  int wkid = (bid & 7) * (nblk / 8) + (bid >> 3);
  int hh = wkid & 1;
  int ksp = (wkid >> 1) % NKS;
  int rest = (wkid >> 1) / NKS;
  int qt = rest & 127, b = rest >> 7;
  int q0 = qt * 16;
  int t = threadIdx.x, w = t >> 6, l = t & 63;
  int l15 = l & 15, lg = l >> 4;
  int h = hh * 4 + w;

  bf16x8 qa[2];
#pragma unroll
  for (int kc = 0; kc < 2; ++kc)
    qa[kc] = *(const bf16x8*)(q + ((size_t)(b * 2048 + q0 + l15) * 512 + h * 64 + kc * 32 + lg * 8));

  f32x4 oacc[4] = {};
  float mrow[4], lrow[4];
#pragma unroll
  for (int r = 0; r < 4; ++r) { mrow[r] = -3e38f; lrow[r] = 0.f; }

  const int kbase0 = ksp * (2048 / NKS);
  const int iters = 2048 / NKS / 32;
  const unsigned short* vbase = vt + ((size_t)(b * 8 + h) * 64) * 2048;
  const unsigned short* bplane = biasT + ((size_t)(b * 8 + h) * 2048 + q0) * 2048;

  for (int it = 0; it < iters; ++it) {
    int kb0 = kbase0 + it * 32;
    // ---- QK^T ----
    f32x4 sc[2] = {};
#pragma unroll
    for (int tt = 0; tt < 2; ++tt) {
      const unsigned short* kp =
          kk + ((size_t)(b * 2048 + kb0 + tt * 16 + l15) * 512 + h * 64 + lg * 8);
      sc[tt] = mfma16(qa[0], *(const bf16x8*)kp, sc[tt]);
      sc[tt] = mfma16(qa[1], *(const bf16x8*)(kp + 32), sc[tt]);
    }
    // ---- bias (bf16 planes, interleaved pairs, mask pre-folded) ----
    float s0v[4], s1v[4], mtile[4];
#pragma unroll
    for (int r = 0; r < 4; ++r) {
      unsigned bw = *(const unsigned*)(bplane + (size_t)(lg * 4 + r) * 2048 + kb0 + l15 * 2);
      float s0 = sc[0][r] + bs2f((unsigned short)(bw & 0xffff));
      float s1 = sc[1][r] + bs2f((unsigned short)(bw >> 16));
      s0v[r] = s0; s1v[r] = s1;
      float mx = fmaxf(s0, s1);
#pragma unroll
      for (int o = 1; o < 16; o <<= 1) mx = fmaxf(mx, __shfl_xor(mx, o));
      mtile[r] = mx;
    }
    float scale[4];
#pragma unroll
    for (int r = 0; r < 4; ++r) {
      float mn = fmaxf(mrow[r], mtile[r]);
      scale[r] = __expf(mrow[r] - mn);
      mrow[r] = mn;
      float p0 = __expf(s0v[r] - mn), p1 = __expf(s1v[r] - mn);
      s0v[r] = p0; s1v[r] = p1;
      float ps = p0 + p1;
#pragma unroll
      for (int o = 1; o < 16; o <<= 1) ps += __shfl_xor(ps, o);
      lrow[r] = lrow[r] * scale[r] + ps;
    }
#pragma unroll
    for (int d = 0; d < 4; ++d)
#pragma unroll
      for (int r = 0; r < 4; ++r) oacc[d][r] *= scale[r];
#pragma unroll
    for (int r = 0; r < 4; ++r) {
      ls_p[w][lg * 4 + r][l15] = f2bs(s0v[r]);
      ls_p[w][lg * 4 + r][16 + l15] = f2bs(s1v[r]);
    }
    bf16x8 pa = *(const bf16x8*)&ls_p[w][l15][lg * 8];
#pragma unroll
    for (int d = 0; d < 4; ++d) {
      const unsigned short* vp = vbase + ((size_t)(d * 16 + l15) * 2048 + kb0 + lg * 8);
      oacc[d] = mfma16(pa, *(const bf16x8*)vp, oacc[d]);
    }
  }
#pragma unroll
  for (int d = 0; d < 4; ++d)
#pragma unroll
    for (int r = 0; r < 4; ++r) {
      size_t row = (size_t)(ksp * 4096 + b * 2048 + q0 + lg * 4 + r);
      opart[row * 512 + h * 64 + d * 16 + l15] = f2bs(oacc[d][r]);
    }
  if (l15 == 0) {
#pragma unroll
    for (int r = 0; r < 4; ++r) {
      size_t row = (size_t)(ksp * 4096 + b * 2048 + q0 + lg * 4 + r);
      mpart[row * 8 + h] = mrow[r];
      lpart[row * 8 + h] = lrow[r];
    }
  }
}

// ---------------- legacy flash attention (f32 bias gather) for small-ws fallback ----------------
template <int NKS>
__global__ __launch_bounds__(256, 4) void k_attn2f(
    const unsigned short* __restrict__ q, const unsigned short* __restrict__ kk,
    const unsigned short* __restrict__ vt, const float* __restrict__ bias,
    const unsigned char* __restrict__ mask, unsigned short* __restrict__ opart,
    float* __restrict__ mpart, float* __restrict__ lpart) {
  __shared__ unsigned short ls_p[4][16][36];
  const int nblk = 512 * NKS;
  int bid = blockIdx.x;
  int wkid = (bid & 7) * (nblk / 8) + (bid >> 3);
  int hh = wkid & 1;
  int ksp = (wkid >> 1) % NKS;
  int rest = (wkid >> 1) / NKS;
  int qt = rest & 127, b = rest >> 7;
  int q0 = qt * 16;
  int t = threadIdx.x, w = t >> 6, l = t & 63;
  int l15 = l & 15, lg = l >> 4;
  int h = hh * 4 + w;
  bf16x8 qa[2];
#pragma unroll
  for (int kc = 0; kc < 2; ++kc)
    qa[kc] = *(const bf16x8*)(q + ((size_t)(b * 2048 + q0 + l15) * 512 + h * 64 + kc * 32 + lg * 8));
  f32x4 oacc[4] = {};
  float mrow[4], lrow[4];
#pragma unroll
  for (int r = 0; r < 4; ++r) { mrow[r] = -3e38f; lrow[r] = 0.f; }
  const int kbase0 = ksp * (2048 / NKS);
  const int iters = 2048 / NKS / 32;
  const unsigned short* vbase = vt + ((size_t)(b * 8 + h) * 64) * 2048;
  for (int it = 0; it < iters; ++it) {
    int kb0 = kbase0 + it * 32;
    f32x4 sc[2] = {};
#pragma unroll
    for (int tt = 0; tt < 2; ++tt) {
      const unsigned short* kp =
          kk + ((size_t)(b * 2048 + kb0 + tt * 16 + l15) * 512 + h * 64 + lg * 8);
      sc[tt] = mfma16(qa[0], *(const bf16x8*)kp, sc[tt]);
      sc[tt] = mfma16(qa[1], *(const bf16x8*)(kp + 32), sc[tt]);
    }
    float s0v[4], s1v[4], mtile[4];
#pragma unroll
    for (int r = 0; r < 4; ++r) {
      size_t grow = (size_t)(b * 2048 + q0 + lg * 4 + r) * 2048 + kb0;
      float b0 = bias[(grow + l15) * 8 + h];
      float b1 = bias[(grow + 16 + l15) * 8 + h];
      float s0 = sc[0][r] + b0, s1 = sc[1][r] + b1;
      if (mask[grow + l15]) s0 = -3e38f;
      if (mask[grow + 16 + l15]) s1 = -3e38f;
      s0v[r] = s0; s1v[r] = s1;
      float mx = fmaxf(s0, s1);
#pragma unroll
      for (int o = 1; o < 16; o <<= 1) mx = fmaxf(mx, __shfl_xor(mx, o));
      mtile[r] = mx;
    }
    float scale[4];
#pragma unroll
    for (int r = 0; r < 4; ++r) {
      float mn = fmaxf(mrow[r], mtile[r]);
      scale[r] = __expf(mrow[r] - mn);
      mrow[r] = mn;
      float p0 = __expf(s0v[r] - mn), p1 = __expf(s1v[r] - mn);
      s0v[r] = p0; s1v[r] = p1;
      float ps = p0 + p1;
#pragma unroll
      for (int o = 1; o < 16; o <<= 1) ps += __shfl_xor(ps, o);
      lrow[r] = lrow[r] * scale[r] + ps;
    }
#pragma unroll
    for (int d = 0; d < 4; ++d)
#pragma unroll
      for (int r = 0; r < 4; ++r) oacc[d][r] *= scale[r];
#pragma unroll
    for (int r = 0; r < 4; ++r) {
      ls_p[w][lg * 4 + r][l15] = f2bs(s0v[r]);
      ls_p[w][lg * 4 + r][16 + l15] = f2bs(s1v[r]);
    }
    bf16x8 pa = *(const bf16x8*)&ls_p[w][l15][lg * 8];
#pragma unroll
    for (int d = 0; d < 4; ++d) {
      const unsigned short* vp = vbase + ((size_t)(d * 16 + l15) * 2048 + kb0 + lg * 8);
      oacc[d] = mfma16(pa, *(const bf16x8*)vp, oacc[d]);
    }
  }
#pragma unroll
  for (int d = 0; d < 4; ++d)
#pragma unroll
    for (int r = 0; r < 4; ++r) {
      size_t row = (size_t)(ksp * 4096 + b * 2048 + q0 + lg * 4 + r);
      opart[row * 512 + h * 64 + d * 16 + l15] = f2bs(oacc[d][r]);
    }
  if (l15 == 0) {
#pragma unroll
    for (int r = 0; r < 4; ++r) {
      size_t row = (size_t)(ksp * 4096 + b * 2048 + q0 + lg * 4 + r);
      mpart[row * 8 + h] = mrow[r];
      lpart[row * 8 + h] = lrow[r];
    }
  }
}

// ---------------- combine k-split partials ----------------
template <int NKS>
__global__ __launch_bounds__(256) void k_comb(const unsigned short* __restrict__ op,
                                              const float* __restrict__ mp,
                                              const float* __restrict__ lp,
                                              unsigned short* __restrict__ ao) {
  int row = blockIdx.x, t = threadIdx.x;
  for (int c = t; c < 512; c += 256) {
    int h = c >> 6;
    float M = -3e38f;
#pragma unroll
    for (int s = 0; s < NKS; ++s)
      M = fmaxf(M, mp[(size_t)(s * 4096 + row) * 8 + h]);
    float L = 0.f, o = 0.f;
#pragma unroll
    for (int s = 0; s < NKS; ++s) {
      float e = __expf(mp[(size_t)(s * 4096 + row) * 8 + h] - M);
      L += lp[(size_t)(s * 4096 + row) * 8 + h] * e;
      o += bs2f(op[(size_t)(s * 4096 + row) * 512 + c]) * e;
    }
    ao[(size_t)row * 512 + c] = f2bs(o / L);
  }
}

extern "C" void kernel_launch(void* const* d_in, const int* in_sizes, int n_in,
                              void* d_out, int out_size, void* d_ws, size_t ws_size,
                              hipStream_t stream) {
  (void)in_sizes; (void)n_in; (void)out_size;
  const float* x = (const float*)d_in[0];
  const float* abias = (const float*)d_in[1];
  const unsigned char* amask = (const unsigned char*)d_in[2];
  const float* Wq = (const float*)d_in[3];
  const float* bq = (const float*)d_in[4];
  const float* Wk = (const float*)d_in[5];
  const float* bk = (const float*)d_in[6];
  const float* Wv = (const float*)d_in[7];
  const float* bv = (const float*)d_in[8];
  const float* Wg = (const float*)d_in[9];
  const float* bg = (const float*)d_in[10];
  const float* Wo = (const float*)d_in[11];
  const float* bo = (const float*)d_in[12];
  const float* ln1g = (const float*)d_in[13];
  const float* ln1b = (const float*)d_in[14];
  const float* ln2g = (const float*)d_in[15];
  const float* ln2b = (const float*)d_in[16];
  const float* W1 = (const float*)d_in[17];
  const float* b1 = (const float*)d_in[18];
  const float* W2 = (const float*)d_in[19];
  const float* b2 = (const float*)d_in[20];
  float* outp = (float*)d_out;

  char* ws = (char*)d_ws;
  const size_t MB = 1024 * 1024;
  const bool bigws = ws_size >= (size_t)192 * MB;

  unsigned short* qb = (unsigned short*)(ws + 0);          // 4MB
  unsigned short* kb = (unsigned short*)(ws + 4 * MB);     // 4MB
  unsigned short* ao = (unsigned short*)(ws + 8 * MB);     // 4MB
  unsigned short* opart = (unsigned short*)(ws + 12 * MB); // up to 16MB (12-28)
  unsigned short* y1 = (unsigned short*)(ws + 28 * MB);    // 4MB
  unsigned short* h1 = (unsigned short*)(ws + 0);          // 16MB FFN phase
  float* u = (float*)(ws + 32 * MB);                       // 8MB
  unsigned short* wcat = (unsigned short*)(ws + 40 * MB);  // 2MB
  unsigned short* wot = (unsigned short*)(ws + 42 * MB);   // 0.5MB
  unsigned short* w1t = (unsigned short*)(ws + 42 * MB + 512 * 1024);
  unsigned short* w2t = (unsigned short*)(ws + 44 * MB + 512 * 1024);
  float* bcat = (float*)(ws + 46 * MB + 512 * 1024);
  float* mpart = (float*)(ws + 47 * MB);                   // 512KB
  float* lpart = (float*)(ws + 47 * MB + 512 * 1024);      // 512KB
  unsigned short* vtb = (unsigned short*)(ws + 48 * MB);   // 4MB
  unsigned short* biasT = (unsigned short*)(ws + 64 * MB); // 128MB (bigws only)
  float* x2 = (float*)d_out;

  k_transw<<<dim3(8, 8), 256, 0, stream>>>(Wq, wcat + 0 * 512 * 512, 512, 512);
  k_transw<<<dim3(8, 8), 256, 0, stream>>>(Wk, wcat + 1 * 512 * 512, 512, 512);
  k_transw<<<dim3(8, 8), 256, 0, stream>>>(Wv, wcat + 2 * 512 * 512, 512, 512);
  k_transw<<<dim3(8, 8), 256, 0, stream>>>(Wg, wcat + 3 * 512 * 512, 512, 512);
  k_transw<<<dim3(8, 8), 256, 0, stream>>>(Wo, wot, 512, 512);
  k_transw<<<dim3(8, 32), 256, 0, stream>>>(W1, w1t, 512, 2048);
  k_transw<<<dim3(32, 8), 256, 0, stream>>>(W2, w2t, 2048, 512);
  k_bcat<<<8, 256, 0, stream>>>(bq, bk, bv, bg, bcat);

  if (bigws)
    k_btrans<<<32768, 256, 0, stream>>>(abias, amask, biasT);

  k_ln<<<4096, 256, 0, stream>>>(x, ln1g, ln1b, y1);
  k_gemm<128><<<dim3(32, 32), 256, 0, stream>>>(y1, wcat, bcat, 4096, 2048, 512, 6,
                                                u, qb, nullptr, nullptr, vtb);
  if (bigws) {
    k_attn3<4><<<2048, 256, 0, stream>>>(qb, kb, vtb, biasT, opart, mpart, lpart);
    k_comb<4><<<4096, 256, 0, stream>>>(opart, mpart, lpart, ao);
  } else {
    k_attn2f<2><<<1024, 256, 0, stream>>>(qb, kb, vtb, abias, amask, opart, mpart, lpart);
    k_comb<2><<<4096, 256, 0, stream>>>(opart, mpart, lpart, ao);
  }
  k_gemm<64><<<dim3(64, 8), 256, 0, stream>>>(ao, wot, bo, 4096, 512, 512, 3,
                                              x2, nullptr, u, x, nullptr);
  k_ln<<<4096, 256, 0, stream>>>(x2, ln2g, ln2b, y1);
  k_gemm<128><<<dim3(32, 32), 256, 0, stream>>>(y1, w1t, b1, 4096, 2048, 512, 4,
                                                nullptr, h1, nullptr, nullptr, nullptr);
  k_gemm<64><<<dim3(64, 8), 256, 0, stream>>>(h1, w2t, b2, 4096, 512, 2048, 5,
                                              outp, nullptr, x2, nullptr, nullptr);
}

// Round 4
// 358.739 us; speedup vs baseline: 1.2904x; 1.0364x over previous
//
#include <hip/hip_runtime.h>
#include <hip/hip_bf16.h>

#define DI __device__ __forceinline__

typedef __attribute__((ext_vector_type(8))) __bf16 bf16x8;
typedef __attribute__((ext_vector_type(4))) float f32x4;
typedef __attribute__((ext_vector_type(4))) unsigned short u16x4;

DI unsigned short f2bs(float f) {
  __hip_bfloat16 h = __float2bfloat16(f);
  return __builtin_bit_cast(unsigned short, h);
}
DI float bs2f(unsigned short s) {
  return __bfloat162float(__builtin_bit_cast(__hip_bfloat16, s));
}
DI f32x4 mfma16(bf16x8 a, bf16x8 b, f32x4 c) {
  return __builtin_amdgcn_mfma_f32_16x16x32_bf16(a, b, c, 0, 0, 0);
}
DI void g2lds16(const void* g, void* l) {
  __builtin_amdgcn_global_load_lds(
      (__attribute__((address_space(1))) void*)(unsigned long long)g,
      (__attribute__((address_space(3))) void*)l, 16, 0, 0);
}

// ---------------- weight transpose f32[K,N] -> bf16[N,K] ----------------
__global__ __launch_bounds__(256) void k_transw(const float* __restrict__ W,
                                                unsigned short* __restrict__ Wt,
                                                int K, int N) {
  __shared__ float tile[64][65];
  int tk = blockIdx.x * 64, tn = blockIdx.y * 64;
  int t = threadIdx.x;
#pragma unroll
  for (int i = 0; i < 16; ++i) {
    int idx = t + i * 256;
    int r = idx >> 6, c = idx & 63;
    tile[r][c] = W[(size_t)(tk + r) * N + tn + c];
  }
  __syncthreads();
#pragma unroll
  for (int i = 0; i < 16; ++i) {
    int idx = t + i * 256;
    int n = idx >> 6, kk = idx & 63;
    Wt[(size_t)(tn + n) * K + tk + kk] = f2bs(tile[kk][n]);
  }
}

// ---------------- bias concat [bq|bk|bv|bg] -> bcat[2048] ----------------
__global__ __launch_bounds__(256) void k_bcat(const float* __restrict__ bq,
                                              const float* __restrict__ bk,
                                              const float* __restrict__ bv,
                                              const float* __restrict__ bg,
                                              float* __restrict__ bcat) {
  int t = blockIdx.x * 256 + threadIdx.x;
  const float* src = t < 512 ? bq : t < 1024 ? bk : t < 1536 ? bv : bg;
  bcat[t] = src[t & 511];
}

// ---------------- attn-bias transpose+mask-fold+interleave ----------------
// out: biasT [B,H,Nq,Nk'] bf16; within each 32-col chunk order is (c0,c16,c1,c17,...)
__global__ __launch_bounds__(256) void k_btrans(const float* __restrict__ bias,
                                                const unsigned char* __restrict__ mask,
                                                unsigned short* __restrict__ biasT) {
  int bid = blockIdx.x;
  int kc0 = (bid & 7) * 256;
  int row = (bid >> 3) & 2047;
  int b = bid >> 14;
  int t = threadIdx.x, h = t & 7, g = t >> 3;
  int base2 = kc0 + (g >> 2) * 32 + (g & 3) * 4;
  size_t rowoff = (size_t)(b * 2048 + row) * 2048;
  size_t gidx = (rowoff + base2) * 8 + h;
  unsigned m_lo = *(const unsigned*)(mask + rowoff + base2);
  unsigned m_hi = *(const unsigned*)(mask + rowoff + base2 + 16);
  u16x4 pk[2];
#pragma unroll
  for (int j = 0; j < 4; ++j) {
    float lo = bias[gidx + (size_t)j * 8];
    float hi = bias[gidx + 128 + (size_t)j * 8];
    if ((m_lo >> (8 * j)) & 255) lo = -1e30f;
    if ((m_hi >> (8 * j)) & 255) hi = -1e30f;
    pk[j >> 1][(j & 1) * 2] = f2bs(lo);
    pk[j >> 1][(j & 1) * 2 + 1] = f2bs(hi);
  }
  unsigned short* dst = biasT + ((size_t)(b * 8 + h) * 2048 + row) * 2048 + kc0 + g * 8;
  *(u16x4*)dst = pk[0];
  *(u16x4*)(dst + 4) = pk[1];
}

// ---------------- LayerNorm f32[rows,512] -> bf16 ----------------
__global__ __launch_bounds__(256) void k_ln(const float* __restrict__ x,
                                            const float* __restrict__ g,
                                            const float* __restrict__ b,
                                            unsigned short* __restrict__ y) {
  int row = blockIdx.x, t = threadIdx.x;
  const float* xr = x + (size_t)row * 512;
  float a0 = xr[t], a1 = xr[t + 256];
  float s1 = a0 + a1, s2 = a0 * a0 + a1 * a1;
#pragma unroll
  for (int o = 32; o > 0; o >>= 1) {
    s1 += __shfl_down(s1, o);
    s2 += __shfl_down(s2, o);
  }
  __shared__ float r1[4], r2[4], bc[2];
  int w = t >> 6, l = t & 63;
  if (l == 0) { r1[w] = s1; r2[w] = s2; }
  __syncthreads();
  if (t == 0) {
    float t1 = r1[0] + r1[1] + r1[2] + r1[3];
    float t2 = r2[0] + r2[1] + r2[2] + r2[3];
    float m = t1 / 512.f;
    float v = t2 / 512.f - m * m;
    bc[0] = m;
    bc[1] = rsqrtf(v + 1e-5f);
  }
  __syncthreads();
  float m = bc[0], inv = bc[1];
  y[(size_t)row * 512 + t] = f2bs((a0 - m) * inv * g[t] + b[t]);
  y[(size_t)row * 512 + t + 256] = f2bs((a1 - m) * inv * g[t + 256] + b[t + 256]);
}

// ---------------- GEMM: C[M,N] = A[M,K](bf16) * Bt[N,K]^T + bias ----------------
template <int BM>
__global__ __launch_bounds__(256) void k_gemm(
    const unsigned short* __restrict__ A, const unsigned short* __restrict__ Bt,
    const float* __restrict__ bias, int M, int N, int K, int mode,
    float* __restrict__ outf, unsigned short* __restrict__ outh,
    const float* __restrict__ add1, const float* __restrict__ add2,
    unsigned short* __restrict__ vtout) {
  constexpr int MI = BM / 32;
  __shared__ __align__(16) unsigned short lA[BM * 64];
  __shared__ __align__(16) unsigned short lB[64 * 64];
  int t = threadIdx.x, w = t >> 6, l = t & 63;
  int l15 = l & 15, lg = l >> 4;
  int m0 = blockIdx.x * BM, n0 = blockIdx.y * 64;
  int wm = (w >> 1) * (BM / 2), wn = (w & 1) * 32;
  f32x4 acc[MI][2] = {};
  int sr = l >> 3, scb = (l & 7) * 16;
  for (int k0 = 0; k0 < K; k0 += 64) {
#pragma unroll
    for (int c = 0; c < MI; ++c) {
      int row = w * (BM / 4) + sr + c * 8;
      g2lds16((const char*)A + ((size_t)(m0 + row) * K + k0) * 2 + scb,
              (char*)lA + w * (BM / 4) * 128 + c * 1024);
    }
#pragma unroll
    for (int c = 0; c < 2; ++c) {
      int row = w * 16 + sr + c * 8;
      g2lds16((const char*)Bt + ((size_t)(n0 + row) * K + k0) * 2 + scb,
              (char*)lB + w * 2048 + c * 1024);
    }
    __syncthreads();
#pragma unroll
    for (int kc = 0; kc < 2; ++kc) {
      bf16x8 af[MI], bfr[2];
#pragma unroll
      for (int i = 0; i < MI; ++i)
        af[i] = *(const bf16x8*)((const char*)lA + (wm + i * 16 + l15) * 128 + kc * 64 + lg * 16);
#pragma unroll
      for (int j = 0; j < 2; ++j)
        bfr[j] = *(const bf16x8*)((const char*)lB + (wn + j * 16 + l15) * 128 + kc * 64 + lg * 16);
#pragma unroll
      for (int i = 0; i < MI; ++i)
#pragma unroll
        for (int j = 0; j < 2; ++j)
          acc[i][j] = mfma16(af[i], bfr[j], acc[i][j]);
    }
    __syncthreads();
  }
#pragma unroll
  for (int i = 0; i < MI; ++i) {
#pragma unroll
    for (int j = 0; j < 2; ++j) {
      int col = n0 + wn + j * 16 + l15;
      int row0 = m0 + wm + i * 16 + lg * 4;
      float vals[4];
#pragma unroll
      for (int r = 0; r < 4; ++r) vals[r] = acc[i][j][r] + bias[col];
      if (mode == 6) {
        int sel = col >> 9, c5 = col & 511;
        if (sel == 2) {
          int hh = c5 >> 6, dd = c5 & 63, bb = row0 >> 11, nn = row0 & 2047;
          u16x4 pk;
#pragma unroll
          for (int r = 0; r < 4; ++r) pk[r] = f2bs(vals[r]);
          *(u16x4*)(vtout + (((size_t)(bb * 8 + hh) * 64 + dd) * 2048 + nn)) = pk;
        } else {
#pragma unroll
          for (int r = 0; r < 4; ++r) {
            size_t idx = (size_t)(row0 + r) * 512 + c5;
            if (sel == 0) outh[idx] = f2bs(vals[r] * 0.125f);
            else if (sel == 1) outh[2097152 + idx] = f2bs(vals[r]);
            else outf[idx] = bs2f(A[idx]) * (1.f / (1.f + __expf(-vals[r])));
          }
        }
      } else {
#pragma unroll
        for (int r = 0; r < 4; ++r) {
          size_t idx = (size_t)(row0 + r) * N + col;
          if (mode == 3) outf[idx] = vals[r] + add1[idx] + add2[idx];
          else if (mode == 4) outh[idx] = f2bs(0.5f * vals[r] * (1.f + erff(vals[r] * 0.70710678f)));
          else outf[idx] = vals[r] + add1[idx];
        }
      }
    }
  }
}

// ---------------- flash attention v4: static-max softmax, MFMA row-sum ----------------
// softmax(s) = exp(s-M)/sum(exp(s-M)) exact for any fixed M; masked bias pre-folded
// to -1e30 -> exp -> 0. l accumulated by mfma(P, ones). No cross-lane ops, no barriers.
template <int NKS>
__global__ __launch_bounds__(256, 8) void k_attn4(
    const unsigned short* __restrict__ q, const unsigned short* __restrict__ kk,
    const unsigned short* __restrict__ vt, const unsigned short* __restrict__ biasT,
    unsigned short* __restrict__ opart, float* __restrict__ lpart) {
  __shared__ unsigned short ls_p[2][4][16][36];
  const int nblk = 512 * NKS;
  int bid = blockIdx.x;
  int wkid = (bid & 7) * (nblk / 8) + (bid >> 3);
  int hh = wkid & 1;
  int ksp = (wkid >> 1) % NKS;
  int rest = (wkid >> 1) / NKS;
  int qt = rest & 127, b = rest >> 7;
  int q0 = qt * 16;
  int t = threadIdx.x, w = t >> 6, l = t & 63;
  int l15 = l & 15, lg = l >> 4;
  int h = hh * 4 + w;

  bf16x8 qa[2];
#pragma unroll
  for (int kc = 0; kc < 2; ++kc)
    qa[kc] = *(const bf16x8*)(q + ((size_t)(b * 2048 + q0 + l15) * 512 + h * 64 + kc * 32 + lg * 8));

  union { bf16x8 v; unsigned short s[8]; } uo;
#pragma unroll
  for (int j = 0; j < 8; ++j) uo.s[j] = 0x3F80;  // bf16 1.0
  const bf16x8 vones = uo.v;

  f32x4 oacc[4] = {};
  f32x4 lacc = {};

  const int kbase0 = ksp * (2048 / NKS);
  const int iters = 2048 / NKS / 32;
  const unsigned short* vbase = vt + ((size_t)(b * 8 + h) * 64) * 2048;
  const unsigned short* bplane = biasT + ((size_t)(b * 8 + h) * 2048 + q0) * 2048;

  for (int it = 0; it < iters; ++it) {
    int kb0 = kbase0 + it * 32;
    int pb = it & 1;
    // ---- QK^T ----
    f32x4 sc[2] = {};
#pragma unroll
    for (int tt = 0; tt < 2; ++tt) {
      const unsigned short* kp =
          kk + ((size_t)(b * 2048 + kb0 + tt * 16 + l15) * 512 + h * 64 + lg * 8);
      sc[tt] = mfma16(qa[0], *(const bf16x8*)kp, sc[tt]);
      sc[tt] = mfma16(qa[1], *(const bf16x8*)(kp + 32), sc[tt]);
    }
    // ---- bias add + static-max exp ----
#pragma unroll
    for (int r = 0; r < 4; ++r) {
      unsigned bw = *(const unsigned*)(bplane + (size_t)(lg * 4 + r) * 2048 + kb0 + l15 * 2);
      float p0 = __expf(sc[0][r] + bs2f((unsigned short)(bw & 0xffff)) - 8.0f);
      float p1 = __expf(sc[1][r] + bs2f((unsigned short)(bw >> 16)) - 8.0f);
      ls_p[pb][w][lg * 4 + r][l15] = f2bs(p0);
      ls_p[pb][w][lg * 4 + r][16 + l15] = f2bs(p1);
    }
    // ---- PV + rowsum (A-frag re-read; compiler inserts lgkmcnt) ----
    bf16x8 pa = *(const bf16x8*)&ls_p[pb][w][l15][lg * 8];
#pragma unroll
    for (int d = 0; d < 4; ++d) {
      const unsigned short* vp = vbase + ((size_t)(d * 16 + l15) * 2048 + kb0 + lg * 8);
      oacc[d] = mfma16(pa, *(const bf16x8*)vp, oacc[d]);
    }
    lacc = mfma16(pa, vones, lacc);
  }
#pragma unroll
  for (int d = 0; d < 4; ++d)
#pragma unroll
    for (int r = 0; r < 4; ++r) {
      size_t row = (size_t)(ksp * 4096 + b * 2048 + q0 + lg * 4 + r);
      opart[row * 512 + h * 64 + d * 16 + l15] = f2bs(oacc[d][r]);
    }
  if (l15 == 0) {
#pragma unroll
    for (int r = 0; r < 4; ++r) {
      size_t row = (size_t)(ksp * 4096 + b * 2048 + q0 + lg * 4 + r);
      lpart[row * 8 + h] = lacc[r];
    }
  }
}

// ---------------- combine k-split partials (static-max: plain sums) ----------------
template <int NKS>
__global__ __launch_bounds__(256) void k_comb2(const unsigned short* __restrict__ op,
                                               const float* __restrict__ lp,
                                               unsigned short* __restrict__ ao) {
  int row = blockIdx.x, t = threadIdx.x;
  for (int c = t; c < 512; c += 256) {
    int h = c >> 6;
    float L = 0.f, o = 0.f;
#pragma unroll
    for (int s = 0; s < NKS; ++s) {
      L += lp[(size_t)(s * 4096 + row) * 8 + h];
      o += bs2f(op[(size_t)(s * 4096 + row) * 512 + c]);
    }
    ao[(size_t)row * 512 + c] = f2bs(o / L);
  }
}

// ---------------- legacy flash attention (f32 bias gather) small-ws fallback ----------------
template <int NKS>
__global__ __launch_bounds__(256, 4) void k_attn2f(
    const unsigned short* __restrict__ q, const unsigned short* __restrict__ kk,
    const unsigned short* __restrict__ vt, const float* __restrict__ bias,
    const unsigned char* __restrict__ mask, unsigned short* __restrict__ opart,
    float* __restrict__ mpart, float* __restrict__ lpart) {
  __shared__ unsigned short ls_p[4][16][36];
  const int nblk = 512 * NKS;
  int bid = blockIdx.x;
  int wkid = (bid & 7) * (nblk / 8) + (bid >> 3);
  int hh = wkid & 1;
  int ksp = (wkid >> 1) % NKS;
  int rest = (wkid >> 1) / NKS;
  int qt = rest & 127, b = rest >> 7;
  int q0 = qt * 16;
  int t = threadIdx.x, w = t >> 6, l = t & 63;
  int l15 = l & 15, lg = l >> 4;
  int h = hh * 4 + w;
  bf16x8 qa[2];
#pragma unroll
  for (int kc = 0; kc < 2; ++kc)
    qa[kc] = *(const bf16x8*)(q + ((size_t)(b * 2048 + q0 + l15) * 512 + h * 64 + kc * 32 + lg * 8));
  f32x4 oacc[4] = {};
  float mrow[4], lrow[4];
#pragma unroll
  for (int r = 0; r < 4; ++r) { mrow[r] = -3e38f; lrow[r] = 0.f; }
  const int kbase0 = ksp * (2048 / NKS);
  const int iters = 2048 / NKS / 32;
  const unsigned short* vbase = vt + ((size_t)(b * 8 + h) * 64) * 2048;
  for (int it = 0; it < iters; ++it) {
    int kb0 = kbase0 + it * 32;
    f32x4 sc[2] = {};
#pragma unroll
    for (int tt = 0; tt < 2; ++tt) {
      const unsigned short* kp =
          kk + ((size_t)(b * 2048 + kb0 + tt * 16 + l15) * 512 + h * 64 + lg * 8);
      sc[tt] = mfma16(qa[0], *(const bf16x8*)kp, sc[tt]);
      sc[tt] = mfma16(qa[1], *(const bf16x8*)(kp + 32), sc[tt]);
    }
    float s0v[4], s1v[4], mtile[4];
#pragma unroll
    for (int r = 0; r < 4; ++r) {
      size_t grow = (size_t)(b * 2048 + q0 + lg * 4 + r) * 2048 + kb0;
      float b0 = bias[(grow + l15) * 8 + h];
      float b1 = bias[(grow + 16 + l15) * 8 + h];
      float s0 = sc[0][r] + b0, s1 = sc[1][r] + b1;
      if (mask[grow + l15]) s0 = -3e38f;
      if (mask[grow + 16 + l15]) s1 = -3e38f;
      s0v[r] = s0; s1v[r] = s1;
      float mx = fmaxf(s0, s1);
#pragma unroll
      for (int o = 1; o < 16; o <<= 1) mx = fmaxf(mx, __shfl_xor(mx, o));
      mtile[r] = mx;
    }
    float scale[4];
#pragma unroll
    for (int r = 0; r < 4; ++r) {
      float mn = fmaxf(mrow[r], mtile[r]);
      scale[r] = __expf(mrow[r] - mn);
      mrow[r] = mn;
      float p0 = __expf(s0v[r] - mn), p1 = __expf(s1v[r] - mn);
      s0v[r] = p0; s1v[r] = p1;
      float ps = p0 + p1;
#pragma unroll
      for (int o = 1; o < 16; o <<= 1) ps += __shfl_xor(ps, o);
      lrow[r] = lrow[r] * scale[r] + ps;
    }
#pragma unroll
    for (int d = 0; d < 4; ++d)
#pragma unroll
      for (int r = 0; r < 4; ++r) oacc[d][r] *= scale[r];
#pragma unroll
    for (int r = 0; r < 4; ++r) {
      ls_p[w][lg * 4 + r][l15] = f2bs(s0v[r]);
      ls_p[w][lg * 4 + r][16 + l15] = f2bs(s1v[r]);
    }
    bf16x8 pa = *(const bf16x8*)&ls_p[w][l15][lg * 8];
#pragma unroll
    for (int d = 0; d < 4; ++d) {
      const unsigned short* vp = vbase + ((size_t)(d * 16 + l15) * 2048 + kb0 + lg * 8);
      oacc[d] = mfma16(pa, *(const bf16x8*)vp, oacc[d]);
    }
  }
#pragma unroll
  for (int d = 0; d < 4; ++d)
#pragma unroll
    for (int r = 0; r < 4; ++r) {
      size_t row = (size_t)(ksp * 4096 + b * 2048 + q0 + lg * 4 + r);
      opart[row * 512 + h * 64 + d * 16 + l15] = f2bs(oacc[d][r]);
    }
  if (l15 == 0) {
#pragma unroll
    for (int r = 0; r < 4; ++r) {
      size_t row = (size_t)(ksp * 4096 + b * 2048 + q0 + lg * 4 + r);
      mpart[row * 8 + h] = mrow[r];
      lpart[row * 8 + h] = lrow[r];
    }
  }
}

template <int NKS>
__global__ __launch_bounds__(256) void k_comb(const unsigned short* __restrict__ op,
                                              const float* __restrict__ mp,
                                              const float* __restrict__ lp,
                                              unsigned short* __restrict__ ao) {
  int row = blockIdx.x, t = threadIdx.x;
  for (int c = t; c < 512; c += 256) {
    int h = c >> 6;
    float M = -3e38f;
#pragma unroll
    for (int s = 0; s < NKS; ++s)
      M = fmaxf(M, mp[(size_t)(s * 4096 + row) * 8 + h]);
    float L = 0.f, o = 0.f;
#pragma unroll
    for (int s = 0; s < NKS; ++s) {
      float e = __expf(mp[(size_t)(s * 4096 + row) * 8 + h] - M);
      L += lp[(size_t)(s * 4096 + row) * 8 + h] * e;
      o += bs2f(op[(size_t)(s * 4096 + row) * 512 + c]) * e;
    }
    ao[(size_t)row * 512 + c] = f2bs(o / L);
  }
}

extern "C" void kernel_launch(void* const* d_in, const int* in_sizes, int n_in,
                              void* d_out, int out_size, void* d_ws, size_t ws_size,
                              hipStream_t stream) {
  (void)in_sizes; (void)n_in; (void)out_size;
  const float* x = (const float*)d_in[0];
  const float* abias = (const float*)d_in[1];
  const unsigned char* amask = (const unsigned char*)d_in[2];
  const float* Wq = (const float*)d_in[3];
  const float* bq = (const float*)d_in[4];
  const float* Wk = (const float*)d_in[5];
  const float* bk = (const float*)d_in[6];
  const float* Wv = (const float*)d_in[7];
  const float* bv = (const float*)d_in[8];
  const float* Wg = (const float*)d_in[9];
  const float* bg = (const float*)d_in[10];
  const float* Wo = (const float*)d_in[11];
  const float* bo = (const float*)d_in[12];
  const float* ln1g = (const float*)d_in[13];
  const float* ln1b = (const float*)d_in[14];
  const float* ln2g = (const float*)d_in[15];
  const float* ln2b = (const float*)d_in[16];
  const float* W1 = (const float*)d_in[17];
  const float* b1 = (const float*)d_in[18];
  const float* W2 = (const float*)d_in[19];
  const float* b2 = (const float*)d_in[20];
  float* outp = (float*)d_out;

  char* ws = (char*)d_ws;
  const size_t MB = 1024 * 1024;
  const bool bigws = ws_size >= (size_t)192 * MB;

  unsigned short* qb = (unsigned short*)(ws + 0);          // 4MB
  unsigned short* kb = (unsigned short*)(ws + 4 * MB);     // 4MB
  unsigned short* ao = (unsigned short*)(ws + 8 * MB);     // 4MB
  unsigned short* opart = (unsigned short*)(ws + 12 * MB); // up to 16MB (12-28)
  unsigned short* y1 = (unsigned short*)(ws + 28 * MB);    // 4MB
  unsigned short* h1 = (unsigned short*)(ws + 0);          // 16MB FFN phase
  float* u = (float*)(ws + 32 * MB);                       // 8MB
  unsigned short* wcat = (unsigned short*)(ws + 40 * MB);  // 2MB
  unsigned short* wot = (unsigned short*)(ws + 42 * MB);   // 0.5MB
  unsigned short* w1t = (unsigned short*)(ws + 42 * MB + 512 * 1024);
  unsigned short* w2t = (unsigned short*)(ws + 44 * MB + 512 * 1024);
  float* bcat = (float*)(ws + 46 * MB + 512 * 1024);
  float* mpart = (float*)(ws + 47 * MB);                   // 512KB
  float* lpart = (float*)(ws + 47 * MB + 512 * 1024);      // 512KB
  unsigned short* vtb = (unsigned short*)(ws + 48 * MB);   // 4MB
  unsigned short* biasT = (unsigned short*)(ws + 64 * MB); // 128MB (bigws only)
  float* x2 = (float*)d_out;

  k_transw<<<dim3(8, 8), 256, 0, stream>>>(Wq, wcat + 0 * 512 * 512, 512, 512);
  k_transw<<<dim3(8, 8), 256, 0, stream>>>(Wk, wcat + 1 * 512 * 512, 512, 512);
  k_transw<<<dim3(8, 8), 256, 0, stream>>>(Wv, wcat + 2 * 512 * 512, 512, 512);
  k_transw<<<dim3(8, 8), 256, 0, stream>>>(Wg, wcat + 3 * 512 * 512, 512, 512);
  k_transw<<<dim3(8, 8), 256, 0, stream>>>(Wo, wot, 512, 512);
  k_transw<<<dim3(8, 32), 256, 0, stream>>>(W1, w1t, 512, 2048);
  k_transw<<<dim3(32, 8), 256, 0, stream>>>(W2, w2t, 2048, 512);
  k_bcat<<<8, 256, 0, stream>>>(bq, bk, bv, bg, bcat);

  if (bigws)
    k_btrans<<<32768, 256, 0, stream>>>(abias, amask, biasT);

  k_ln<<<4096, 256, 0, stream>>>(x, ln1g, ln1b, y1);
  k_gemm<128><<<dim3(32, 32), 256, 0, stream>>>(y1, wcat, bcat, 4096, 2048, 512, 6,
                                                u, qb, nullptr, nullptr, vtb);
  if (bigws) {
    k_attn4<4><<<2048, 256, 0, stream>>>(qb, kb, vtb, biasT, opart, lpart);
    k_comb2<4><<<4096, 256, 0, stream>>>(opart, lpart, ao);
  } else {
    k_attn2f<2><<<1024, 256, 0, stream>>>(qb, kb, vtb, abias, amask, opart, mpart, lpart);
    k_comb<2><<<4096, 256, 0, stream>>>(opart, mpart, lpart, ao);
  }
  k_gemm<64><<<dim3(64, 8), 256, 0, stream>>>(ao, wot, bo, 4096, 512, 512, 3,
                                              x2, nullptr, u, x, nullptr);
  k_ln<<<4096, 256, 0, stream>>>(x2, ln2g, ln2b, y1);
  k_gemm<128><<<dim3(32, 32), 256, 0, stream>>>(y1, w1t, b1, 4096, 2048, 512, 4,
                                                nullptr, h1, nullptr, nullptr, nullptr);
  k_gemm<64><<<dim3(64, 8), 256, 0, stream>>>(h1, w2t, b2, 4096, 512, 2048, 5,
                                              outp, nullptr, x2, nullptr, nullptr);
}